// Round 2
// baseline (349.201 us; speedup 1.0000x reference)
//
#include <hip/hip_runtime.h>
#include <cstddef>
#include <cstdint>

#define N_NODES 50000
#define N_EDGES 800000
#define IN_CH 128
#define HID 64
#define OUT_CH 32

// ---------------- edge decode (int32 vs int64 decided at runtime) ----------
__device__ __forceinline__ void load_edge(const void* ei, int flag, int e, int& s, int& d) {
    if (flag) {  // int64 data
        const long long* p = (const long long*)ei;
        s = (int)p[e];
        d = (int)p[e + N_EDGES];
    } else {     // int32 data
        const int* p = (const int*)ei;
        s = p[e];
        d = p[e + N_EDGES];
    }
}

// flag=1 iff data is int64: odd int32 words (high halves) are all zero.
__global__ __launch_bounds__(256) void detect_kernel(const unsigned* ei, int* flagp) {
    __shared__ unsigned red[256];
    unsigned acc = 0;
    for (int i = threadIdx.x; i < 2048; i += 256) acc |= ei[2 * i + 1];
    red[threadIdx.x] = acc;
    __syncthreads();
    if (threadIdx.x == 0) {
        unsigned o = 0;
        for (int i = 0; i < 256; ++i) o |= red[i];
        *flagp = (o == 0) ? 1 : 0;
    }
}

__global__ __launch_bounds__(256) void deg_kernel(const void* ei, const int* flagp, int* deg) {
    const int flag = *flagp;
    int e = blockIdx.x * 256 + threadIdx.x;
    if (e < N_EDGES) {
        int s, d;
        load_edge(ei, flag, e, s, d);
        atomicAdd(&deg[d], 1);
    }
}

__global__ __launch_bounds__(256) void dis_kernel(const int* deg, float* dis) {
    int i = blockIdx.x * 256 + threadIdx.x;
    if (i < N_NODES) dis[i] = rsqrtf((float)deg[i] + 1.0f);
}

// ---- exclusive scan of deg -> rowptr[0..N], cursor init. 1 block x 1024. ----
#define SCAN_T 1024
#define SCAN_CHUNK 49  // 1024*49 = 50176 >= 50000
__global__ __launch_bounds__(SCAN_T) void scan_kernel(const int* __restrict__ deg,
                                                      int* __restrict__ rowptr,
                                                      int* __restrict__ cursor) {
    __shared__ int sm[SCAN_T];
    const int t = threadIdx.x;
    const int start = t * SCAN_CHUNK;
    const int end = min(start + SCAN_CHUNK, N_NODES);
    int s = 0;
    for (int i = start; i < end; ++i) s += deg[i];
    sm[t] = s;
    __syncthreads();
    // Hillis-Steele inclusive scan
    for (int off = 1; off < SCAN_T; off <<= 1) {
        int v = (t >= off) ? sm[t - off] : 0;
        __syncthreads();
        sm[t] += v;
        __syncthreads();
    }
    int run = sm[t] - s;  // exclusive prefix
    for (int i = start; i < end; ++i) {
        rowptr[i] = run;
        cursor[i] = run;
        run += deg[i];
    }
    if (t == 0) rowptr[N_NODES] = sm[SCAN_T - 1];
}

// ---- counting-sort scatter: sortedsrc[pos] = src, grouped by dst ----------
__global__ __launch_bounds__(256) void sort_kernel(const void* ei, const int* flagp,
                                                   int* __restrict__ cursor,
                                                   int* __restrict__ sortedsrc) {
    const int flag = *flagp;
    int e = blockIdx.x * 256 + threadIdx.x;
    if (e < N_EDGES) {
        int s, d;
        load_edge(ei, flag, e, s, d);
        int pos = atomicAdd(&cursor[d], 1);
        sortedsrc[pos] = s;
    }
}

// --------------- GEMM1: h1 = x @ W1 -----------------
// tile: 64 rows x 64 cols, K=128. block 256 threads, 4x4 register tile/thread.
__global__ __launch_bounds__(256) void gemm1_kernel(
        const float* __restrict__ x, const float* __restrict__ W1,
        float* __restrict__ h1) {
    extern __shared__ float smem[];
    float (*xs)[132] = (float(*)[132])smem;             // 64 x 132
    float (*wsh)[68] = (float(*)[68])(smem + 64 * 132); // 128 x 68

    const int t = threadIdx.x;
    const int brow = blockIdx.x * 64;

    for (int f = t; f < 2048; f += 256) {
        int r = f >> 4, c = (f & 15) << 2;
        float4 v = ((const float4*)W1)[f];
        *(float4*)&wsh[r][c] = v;
    }
    for (int f = t; f < 2048; f += 256) {
        int r = f >> 5, c = (f & 31) << 2;
        int gr = brow + r;
        float4 v = make_float4(0.f, 0.f, 0.f, 0.f);
        if (gr < N_NODES) v = *(const float4*)(x + gr * IN_CH + c);
        *(float4*)&xs[r][c] = v;
    }
    __syncthreads();

    const int tc = (t & 15) << 2;
    const int tr = (t >> 4) << 2;
    float acc[4][4] = {};
#pragma unroll 4
    for (int k4 = 0; k4 < 32; ++k4) {
        const int k = k4 << 2;
        float xr[4][4], wr[4][4];
#pragma unroll
        for (int i = 0; i < 4; ++i) {
            float4 v = *(const float4*)&xs[tr + i][k];
            xr[i][0] = v.x; xr[i][1] = v.y; xr[i][2] = v.z; xr[i][3] = v.w;
        }
#pragma unroll
        for (int j = 0; j < 4; ++j) {
            float4 v = *(const float4*)&wsh[k + j][tc];
            wr[j][0] = v.x; wr[j][1] = v.y; wr[j][2] = v.z; wr[j][3] = v.w;
        }
#pragma unroll
        for (int i = 0; i < 4; ++i)
#pragma unroll
            for (int c = 0; c < 4; ++c)
                acc[i][c] += xr[i][0] * wr[0][c] + xr[i][1] * wr[1][c]
                           + xr[i][2] * wr[2][c] + xr[i][3] * wr[3][c];
    }

#pragma unroll
    for (int i = 0; i < 4; ++i) {
        int r = brow + tr + i;
        if (r < N_NODES) {
            *(float4*)(h1 + r * HID + tc) =
                make_float4(acc[i][0], acc[i][1], acc[i][2], acc[i][3]);
        }
    }
}

// ---- agg1: per dst node, wave of 64 lanes (= HID channels) ----------------
// agg1[d][c] = relu( sum_j h1[src_j][c]*dis[src_j]*dis[d] + h1[d][c]*dis[d]^2 + b1[c] )
__global__ __launch_bounds__(256) void agg1_kernel(
        const int* __restrict__ rowptr, const int* __restrict__ sortedsrc,
        const float* __restrict__ dis, const float* __restrict__ h1,
        const float* __restrict__ b1, float* __restrict__ agg1) {
    const int lane = threadIdx.x & 63;
    const int d = blockIdx.x * 4 + (threadIdx.x >> 6);
    if (d >= N_NODES) return;
    const int beg = rowptr[d], end = rowptr[d + 1];
    const float dd = dis[d];
    float acc0 = 0.f, acc1 = 0.f;
    int j = beg;
    for (; j + 1 < end; j += 2) {
        int s0 = sortedsrc[j], s1 = sortedsrc[j + 1];
        float n0 = dis[s0] * dd, n1 = dis[s1] * dd;
        acc0 += h1[s0 * HID + lane] * n0;
        acc1 += h1[s1 * HID + lane] * n1;
    }
    if (j < end) {
        int s0 = sortedsrc[j];
        acc0 += h1[s0 * HID + lane] * (dis[s0] * dd);
    }
    float v = acc0 + acc1 + h1[d * HID + lane] * (dd * dd) + b1[lane];
    agg1[d * HID + lane] = fmaxf(v, 0.f);
}

// --------------- GEMM2: h2 = agg1 @ W2 (agg1 already relu'ed) --------------
// tile: 128 rows x 32 cols, K=64. block 256, 4x4 register tile/thread.
__global__ __launch_bounds__(256) void gemm2_kernel(
        const float* __restrict__ agg1, const float* __restrict__ W2,
        float* __restrict__ h2) {
    extern __shared__ float smem[];
    float (*xs)[68] = (float(*)[68])smem;               // 128 x 68
    float (*wsh)[36] = (float(*)[36])(smem + 128 * 68); // 64 x 36

    const int t = threadIdx.x;
    const int brow = blockIdx.x * 128;

    for (int f = t; f < 512; f += 256) {
        int r = f >> 3, c = (f & 7) << 2;
        float4 v = ((const float4*)W2)[f];
        *(float4*)&wsh[r][c] = v;
    }
    for (int f = t; f < 2048; f += 256) {
        int r = f >> 4, c = (f & 15) << 2;
        int gr = brow + r;
        float4 v = make_float4(0.f, 0.f, 0.f, 0.f);
        if (gr < N_NODES) v = *(const float4*)(agg1 + gr * HID + c);
        *(float4*)&xs[r][c] = v;
    }
    __syncthreads();

    const int tc = (t & 7) << 2;
    const int tr = (t >> 3) << 2;
    float acc[4][4] = {};
#pragma unroll 4
    for (int k4 = 0; k4 < 16; ++k4) {
        const int k = k4 << 2;
        float xr[4][4], wr[4][4];
#pragma unroll
        for (int i = 0; i < 4; ++i) {
            float4 v = *(const float4*)&xs[tr + i][k];
            xr[i][0] = v.x; xr[i][1] = v.y; xr[i][2] = v.z; xr[i][3] = v.w;
        }
#pragma unroll
        for (int j = 0; j < 4; ++j) {
            float4 v = *(const float4*)&wsh[k + j][tc];
            wr[j][0] = v.x; wr[j][1] = v.y; wr[j][2] = v.z; wr[j][3] = v.w;
        }
#pragma unroll
        for (int i = 0; i < 4; ++i)
#pragma unroll
            for (int c = 0; c < 4; ++c)
                acc[i][c] += xr[i][0] * wr[0][c] + xr[i][1] * wr[1][c]
                           + xr[i][2] * wr[2][c] + xr[i][3] * wr[3][c];
    }

#pragma unroll
    for (int i = 0; i < 4; ++i) {
        int r = brow + tr + i;
        if (r < N_NODES) {
            *(float4*)(h2 + r * OUT_CH + tc) =
                make_float4(acc[i][0], acc[i][1], acc[i][2], acc[i][3]);
        }
    }
}

// ---- agg2: per dst node, one wave; lanes 0-31 / 32-63 handle edges j/j+1 ---
// out[d][c] = sum_j h2[src_j][c]*norm_j + h2[d][c]*dis[d]^2 + b2[c]
__global__ __launch_bounds__(256) void agg2_kernel(
        const int* __restrict__ rowptr, const int* __restrict__ sortedsrc,
        const float* __restrict__ dis, const float* __restrict__ h2,
        const float* __restrict__ b2, float* __restrict__ out) {
    const int lane = threadIdx.x & 63;
    const int c = lane & 31;
    const int half = lane >> 5;
    const int d = blockIdx.x * 4 + (threadIdx.x >> 6);
    if (d >= N_NODES) return;
    const int beg = rowptr[d], end = rowptr[d + 1];
    const float dd = dis[d];
    float acc = 0.f;
    for (int j = beg + half; j < end; j += 2) {
        int s = sortedsrc[j];
        acc += h2[s * OUT_CH + c] * (dis[s] * dd);
    }
    acc += __shfl_xor(acc, 32, 64);
    if (half == 0) {
        float v = acc + h2[d * OUT_CH + c] * (dd * dd) + b2[c];
        out[d * OUT_CH + c] = v;
    }
}

extern "C" void kernel_launch(void* const* d_in, const int* in_sizes, int n_in,
                              void* d_out, int out_size, void* d_ws, size_t ws_size,
                              hipStream_t stream) {
    const float* x  = (const float*)d_in[0];
    const float* W1 = (const float*)d_in[1];
    const float* b1 = (const float*)d_in[2];
    const float* W2 = (const float*)d_in[3];
    const float* b2 = (const float*)d_in[4];
    const void*  ei = d_in[5];
    float* out = (float*)d_out;

    char* ws = (char*)d_ws;
    int*   flagp     = (int*)ws;                          // 512 B
    int*   deg       = (int*)(ws + 512);                  // 200704 B
    float* dis       = (float*)(ws + 512 + 200704);       // 200704 B
    int*   rowptr    = (int*)(ws + 512 + 2 * 200704);     // 200704 B (50001 used)
    int*   cursor    = (int*)(ws + 512 + 3 * 200704);     // 200704 B
    int*   sortedsrc = (int*)(ws + 512 + 4 * 200704);     // 3.2 MB
    float* h1        = (float*)(ws + 512 + 4 * 200704 + 3200000);  // 12.8 MB
    float* agg1      = h1 + (size_t)N_NODES * HID;        // 12.8 MB
    float* h2        = agg1 + (size_t)N_NODES * HID;      // 6.4 MB

    hipMemsetAsync(deg, 0, N_NODES * sizeof(int), stream);
    detect_kernel<<<1, 256, 0, stream>>>((const unsigned*)ei, flagp);
    deg_kernel<<<(N_EDGES + 255) / 256, 256, 0, stream>>>(ei, flagp, deg);
    dis_kernel<<<(N_NODES + 255) / 256, 256, 0, stream>>>(deg, dis);
    scan_kernel<<<1, SCAN_T, 0, stream>>>(deg, rowptr, cursor);
    sort_kernel<<<(N_EDGES + 255) / 256, 256, 0, stream>>>(ei, flagp, cursor, sortedsrc);

    size_t sh1 = (64 * 132 + 128 * 68) * sizeof(float);
    gemm1_kernel<<<(N_NODES + 63) / 64, 256, sh1, stream>>>(x, W1, h1);

    agg1_kernel<<<(N_NODES + 3) / 4, 256, 0, stream>>>(rowptr, sortedsrc, dis, h1, b1, agg1);

    size_t sh2 = (128 * 68 + 64 * 36) * sizeof(float);
    gemm2_kernel<<<(N_NODES + 127) / 128, 256, sh2, stream>>>(agg1, W2, h2);

    agg2_kernel<<<(N_NODES + 3) / 4, 256, 0, stream>>>(rowptr, sortedsrc, dis, h2, b2, out);
}

// Round 3
// 248.865 us; speedup vs baseline: 1.4032x; 1.4032x over previous
//
#include <hip/hip_runtime.h>
#include <cstddef>
#include <cstdint>

#define N_NODES 50000
#define N_EDGES 800000
#define IN_CH 128
#define HID 64
#define OUT_CH 32

#define SCAN_B 196  // ceil(50000/256)

// ---------------- edge decode (int32 vs int64 decided at runtime) ----------
__device__ __forceinline__ void load_edge(const void* ei, int flag, int e, int& s, int& d) {
    if (flag) {  // int64 data
        const long long* p = (const long long*)ei;
        s = (int)p[e];
        d = (int)p[e + N_EDGES];
    } else {     // int32 data
        const int* p = (const int*)ei;
        s = p[e];
        d = p[e + N_EDGES];
    }
}

// flag=1 iff data is int64: odd int32 words (high halves) are all zero.
__global__ __launch_bounds__(256) void detect_kernel(const unsigned* ei, int* flagp) {
    __shared__ unsigned red[256];
    unsigned acc = 0;
    for (int i = threadIdx.x; i < 2048; i += 256) acc |= ei[2 * i + 1];
    red[threadIdx.x] = acc;
    __syncthreads();
    if (threadIdx.x == 0) {
        unsigned o = 0;
        for (int i = 0; i < 256; ++i) o |= red[i];
        *flagp = (o == 0) ? 1 : 0;
    }
}

__global__ __launch_bounds__(256) void deg_kernel(const void* ei, const int* flagp, int* deg) {
    const int flag = *flagp;
    int e = blockIdx.x * 256 + threadIdx.x;
    if (e < N_EDGES) {
        int s, d;
        load_edge(ei, flag, e, s, d);
        atomicAdd(&deg[d], 1);
    }
}

__global__ __launch_bounds__(256) void dis_kernel(const int* deg, float* dis) {
    int i = blockIdx.x * 256 + threadIdx.x;
    if (i < N_NODES) dis[i] = rsqrtf((float)deg[i] + 1.0f);
}

// ---- scan phase 1: per-block sums of deg (256 elems/block) ----------------
__global__ __launch_bounds__(256) void scan1_kernel(const int* __restrict__ deg,
                                                    int* __restrict__ bsum) {
    __shared__ int sm[256];
    int i = blockIdx.x * 256 + threadIdx.x;
    int v = (i < N_NODES) ? deg[i] : 0;
    sm[threadIdx.x] = v;
    __syncthreads();
#pragma unroll
    for (int off = 128; off > 0; off >>= 1) {
        if (threadIdx.x < off) sm[threadIdx.x] += sm[threadIdx.x + off];
        __syncthreads();
    }
    if (threadIdx.x == 0) bsum[blockIdx.x] = sm[0];
}

// ---- scan phase 2: exclusive scan of the 196 block sums (1 tiny block) ----
__global__ __launch_bounds__(256) void scan2_kernel(const int* __restrict__ bsum,
                                                    int* __restrict__ ebsum) {
    __shared__ int sm[256];
    int t = threadIdx.x;
    int v = (t < SCAN_B) ? bsum[t] : 0;
    sm[t] = v;
    __syncthreads();
#pragma unroll
    for (int off = 1; off < 256; off <<= 1) {
        int u = (t >= off) ? sm[t - off] : 0;
        __syncthreads();
        sm[t] += u;
        __syncthreads();
    }
    if (t < SCAN_B) ebsum[t] = sm[t] - v;  // exclusive
}

// ---- scan phase 3: intra-block exclusive scan + offset -> rowptr, cursor --
__global__ __launch_bounds__(256) void scan3_kernel(const int* __restrict__ deg,
                                                    const int* __restrict__ ebsum,
                                                    int* __restrict__ rowptr,
                                                    int* __restrict__ cursor) {
    __shared__ int sm[256];
    const int t = threadIdx.x;
    const int i = blockIdx.x * 256 + t;
    int v = (i < N_NODES) ? deg[i] : 0;
    sm[t] = v;
    __syncthreads();
#pragma unroll
    for (int off = 1; off < 256; off <<= 1) {
        int u = (t >= off) ? sm[t - off] : 0;
        __syncthreads();
        sm[t] += u;
        __syncthreads();
    }
    int incl = sm[t];
    int base = ebsum[blockIdx.x];
    if (i < N_NODES) {
        int excl = base + incl - v;
        rowptr[i] = excl;
        cursor[i] = excl;
        if (i == N_NODES - 1) rowptr[N_NODES] = base + incl;
    }
}

// ---- counting-sort scatter: sortedsrc[pos] = src, grouped by dst ----------
__global__ __launch_bounds__(256) void sort_kernel(const void* ei, const int* flagp,
                                                   int* __restrict__ cursor,
                                                   int* __restrict__ sortedsrc) {
    const int flag = *flagp;
    int e = blockIdx.x * 256 + threadIdx.x;
    if (e < N_EDGES) {
        int s, d;
        load_edge(ei, flag, e, s, d);
        int pos = atomicAdd(&cursor[d], 1);
        sortedsrc[pos] = s;
    }
}

// --------------- GEMM1: h1 = x @ W1 -----------------
// tile: 64 rows x 64 cols, K=128. block 256 threads, 4x4 register tile/thread.
__global__ __launch_bounds__(256) void gemm1_kernel(
        const float* __restrict__ x, const float* __restrict__ W1,
        float* __restrict__ h1) {
    extern __shared__ float smem[];
    float (*xs)[132] = (float(*)[132])smem;             // 64 x 132
    float (*wsh)[68] = (float(*)[68])(smem + 64 * 132); // 128 x 68

    const int t = threadIdx.x;
    const int brow = blockIdx.x * 64;

    for (int f = t; f < 2048; f += 256) {
        int r = f >> 4, c = (f & 15) << 2;
        float4 v = ((const float4*)W1)[f];
        *(float4*)&wsh[r][c] = v;
    }
    for (int f = t; f < 2048; f += 256) {
        int r = f >> 5, c = (f & 31) << 2;
        int gr = brow + r;
        float4 v = make_float4(0.f, 0.f, 0.f, 0.f);
        if (gr < N_NODES) v = *(const float4*)(x + gr * IN_CH + c);
        *(float4*)&xs[r][c] = v;
    }
    __syncthreads();

    const int tc = (t & 15) << 2;
    const int tr = (t >> 4) << 2;
    float acc[4][4] = {};
#pragma unroll 4
    for (int k4 = 0; k4 < 32; ++k4) {
        const int k = k4 << 2;
        float xr[4][4], wr[4][4];
#pragma unroll
        for (int i = 0; i < 4; ++i) {
            float4 v = *(const float4*)&xs[tr + i][k];
            xr[i][0] = v.x; xr[i][1] = v.y; xr[i][2] = v.z; xr[i][3] = v.w;
        }
#pragma unroll
        for (int j = 0; j < 4; ++j) {
            float4 v = *(const float4*)&wsh[k + j][tc];
            wr[j][0] = v.x; wr[j][1] = v.y; wr[j][2] = v.z; wr[j][3] = v.w;
        }
#pragma unroll
        for (int i = 0; i < 4; ++i)
#pragma unroll
            for (int c = 0; c < 4; ++c)
                acc[i][c] += xr[i][0] * wr[0][c] + xr[i][1] * wr[1][c]
                           + xr[i][2] * wr[2][c] + xr[i][3] * wr[3][c];
    }

#pragma unroll
    for (int i = 0; i < 4; ++i) {
        int r = brow + tr + i;
        if (r < N_NODES) {
            *(float4*)(h1 + r * HID + tc) =
                make_float4(acc[i][0], acc[i][1], acc[i][2], acc[i][3]);
        }
    }
}

// ---- agg1: per dst node, wave of 64 lanes (= HID channels) ----------------
// agg1[d][c] = relu( sum_j h1[src_j][c]*dis[src_j]*dis[d] + h1[d][c]*dis[d]^2 + b1[c] )
__global__ __launch_bounds__(256) void agg1_kernel(
        const int* __restrict__ rowptr, const int* __restrict__ sortedsrc,
        const float* __restrict__ dis, const float* __restrict__ h1,
        const float* __restrict__ b1, float* __restrict__ agg1) {
    const int lane = threadIdx.x & 63;
    const int d = blockIdx.x * 4 + (threadIdx.x >> 6);
    if (d >= N_NODES) return;
    const int beg = rowptr[d], end = rowptr[d + 1];
    const float dd = dis[d];
    float acc0 = 0.f, acc1 = 0.f;
    int j = beg;
    for (; j + 1 < end; j += 2) {
        int s0 = sortedsrc[j], s1 = sortedsrc[j + 1];
        float n0 = dis[s0] * dd, n1 = dis[s1] * dd;
        acc0 += h1[s0 * HID + lane] * n0;
        acc1 += h1[s1 * HID + lane] * n1;
    }
    if (j < end) {
        int s0 = sortedsrc[j];
        acc0 += h1[s0 * HID + lane] * (dis[s0] * dd);
    }
    float v = acc0 + acc1 + h1[d * HID + lane] * (dd * dd) + b1[lane];
    agg1[d * HID + lane] = fmaxf(v, 0.f);
}

// --------------- GEMM2: h2 = agg1 @ W2 (agg1 already relu'ed) --------------
// tile: 128 rows x 32 cols, K=64. block 256, 4x4 register tile/thread.
__global__ __launch_bounds__(256) void gemm2_kernel(
        const float* __restrict__ agg1, const float* __restrict__ W2,
        float* __restrict__ h2) {
    extern __shared__ float smem[];
    float (*xs)[68] = (float(*)[68])smem;               // 128 x 68
    float (*wsh)[36] = (float(*)[36])(smem + 128 * 68); // 64 x 36

    const int t = threadIdx.x;
    const int brow = blockIdx.x * 128;

    for (int f = t; f < 512; f += 256) {
        int r = f >> 3, c = (f & 7) << 2;
        float4 v = ((const float4*)W2)[f];
        *(float4*)&wsh[r][c] = v;
    }
    for (int f = t; f < 2048; f += 256) {
        int r = f >> 4, c = (f & 15) << 2;
        int gr = brow + r;
        float4 v = make_float4(0.f, 0.f, 0.f, 0.f);
        if (gr < N_NODES) v = *(const float4*)(agg1 + gr * HID + c);
        *(float4*)&xs[r][c] = v;
    }
    __syncthreads();

    const int tc = (t & 7) << 2;
    const int tr = (t >> 3) << 2;
    float acc[4][4] = {};
#pragma unroll 4
    for (int k4 = 0; k4 < 16; ++k4) {
        const int k = k4 << 2;
        float xr[4][4], wr[4][4];
#pragma unroll
        for (int i = 0; i < 4; ++i) {
            float4 v = *(const float4*)&xs[tr + i][k];
            xr[i][0] = v.x; xr[i][1] = v.y; xr[i][2] = v.z; xr[i][3] = v.w;
        }
#pragma unroll
        for (int j = 0; j < 4; ++j) {
            float4 v = *(const float4*)&wsh[k + j][tc];
            wr[j][0] = v.x; wr[j][1] = v.y; wr[j][2] = v.z; wr[j][3] = v.w;
        }
#pragma unroll
        for (int i = 0; i < 4; ++i)
#pragma unroll
            for (int c = 0; c < 4; ++c)
                acc[i][c] += xr[i][0] * wr[0][c] + xr[i][1] * wr[1][c]
                           + xr[i][2] * wr[2][c] + xr[i][3] * wr[3][c];
    }

#pragma unroll
    for (int i = 0; i < 4; ++i) {
        int r = brow + tr + i;
        if (r < N_NODES) {
            *(float4*)(h2 + r * OUT_CH + tc) =
                make_float4(acc[i][0], acc[i][1], acc[i][2], acc[i][3]);
        }
    }
}

// ---- agg2: per dst node, one wave; lanes 0-31 / 32-63 handle edges j/j+1 ---
// out[d][c] = sum_j h2[src_j][c]*norm_j + h2[d][c]*dis[d]^2 + b2[c]
__global__ __launch_bounds__(256) void agg2_kernel(
        const int* __restrict__ rowptr, const int* __restrict__ sortedsrc,
        const float* __restrict__ dis, const float* __restrict__ h2,
        const float* __restrict__ b2, float* __restrict__ out) {
    const int lane = threadIdx.x & 63;
    const int c = lane & 31;
    const int half = lane >> 5;
    const int d = blockIdx.x * 4 + (threadIdx.x >> 6);
    if (d >= N_NODES) return;
    const int beg = rowptr[d], end = rowptr[d + 1];
    const float dd = dis[d];
    float acc = 0.f;
    for (int j = beg + half; j < end; j += 2) {
        int s = sortedsrc[j];
        acc += h2[s * OUT_CH + c] * (dis[s] * dd);
    }
    acc += __shfl_xor(acc, 32, 64);
    if (half == 0) {
        float v = acc + h2[d * OUT_CH + c] * (dd * dd) + b2[c];
        out[d * OUT_CH + c] = v;
    }
}

extern "C" void kernel_launch(void* const* d_in, const int* in_sizes, int n_in,
                              void* d_out, int out_size, void* d_ws, size_t ws_size,
                              hipStream_t stream) {
    const float* x  = (const float*)d_in[0];
    const float* W1 = (const float*)d_in[1];
    const float* b1 = (const float*)d_in[2];
    const float* W2 = (const float*)d_in[3];
    const float* b2 = (const float*)d_in[4];
    const void*  ei = d_in[5];
    float* out = (float*)d_out;

    char* ws = (char*)d_ws;
    int*   flagp     = (int*)ws;                          // 512 B
    int*   deg       = (int*)(ws + 512);                  // 200704 B
    float* dis       = (float*)(ws + 512 + 200704);       // 200704 B
    int*   rowptr    = (int*)(ws + 512 + 2 * 200704);     // 200704 B (50001 used)
    int*   cursor    = (int*)(ws + 512 + 3 * 200704);     // 200704 B
    int*   bsum      = (int*)(ws + 512 + 4 * 200704);     // 1024 B
    int*   ebsum     = bsum + 256;                        // 1024 B
    int*   sortedsrc = (int*)(ws + 512 + 4 * 200704 + 4096);  // 3.2 MB
    float* h1        = (float*)(ws + 512 + 4 * 200704 + 4096 + 3200000);  // 12.8 MB
    float* agg1      = h1 + (size_t)N_NODES * HID;        // 12.8 MB
    float* h2        = agg1 + (size_t)N_NODES * HID;      // 6.4 MB

    hipMemsetAsync(deg, 0, N_NODES * sizeof(int), stream);
    detect_kernel<<<1, 256, 0, stream>>>((const unsigned*)ei, flagp);
    deg_kernel<<<(N_EDGES + 255) / 256, 256, 0, stream>>>(ei, flagp, deg);
    dis_kernel<<<(N_NODES + 255) / 256, 256, 0, stream>>>(deg, dis);
    scan1_kernel<<<SCAN_B, 256, 0, stream>>>(deg, bsum);
    scan2_kernel<<<1, 256, 0, stream>>>(bsum, ebsum);
    scan3_kernel<<<SCAN_B, 256, 0, stream>>>(deg, ebsum, rowptr, cursor);
    sort_kernel<<<(N_EDGES + 255) / 256, 256, 0, stream>>>(ei, flagp, cursor, sortedsrc);

    size_t sh1 = (64 * 132 + 128 * 68) * sizeof(float);
    gemm1_kernel<<<(N_NODES + 63) / 64, 256, sh1, stream>>>(x, W1, h1);

    agg1_kernel<<<(N_NODES + 3) / 4, 256, 0, stream>>>(rowptr, sortedsrc, dis, h1, b1, agg1);

    size_t sh2 = (128 * 68 + 64 * 36) * sizeof(float);
    gemm2_kernel<<<(N_NODES + 127) / 128, 256, sh2, stream>>>(agg1, W2, h2);

    agg2_kernel<<<(N_NODES + 3) / 4, 256, 0, stream>>>(rowptr, sortedsrc, dis, h2, b2, out);
}

// Round 4
// 206.573 us; speedup vs baseline: 1.6904x; 1.2047x over previous
//
#include <hip/hip_runtime.h>
#include <hip/hip_bf16.h>
#include <cstddef>
#include <cstdint>

#define N_NODES 50000
#define N_EDGES 800000
#define IN_CH 128
#define HID 64
#define OUT_CH 32

#define SCAN_B 196  // ceil(50000/256)

// bf16 round-to-nearest-even, bit form
__device__ __forceinline__ unsigned short bf16rne(float f) {
    union { float f; unsigned u; } c; c.f = f;
    unsigned r = c.u + 0x7FFF + ((c.u >> 16) & 1);
    return (unsigned short)(r >> 16);
}
__device__ __forceinline__ float bf16f(unsigned short b) {
    union { unsigned u; float f; } c; c.u = ((unsigned)b) << 16;
    return c.f;
}

// ---------------- edge decode (int32 vs int64 decided at runtime) ----------
__device__ __forceinline__ void load_edge(const void* ei, int flag, int e, int& s, int& d) {
    if (flag) {  // int64 data
        const long long* p = (const long long*)ei;
        s = (int)p[e];
        d = (int)p[e + N_EDGES];
    } else {     // int32 data
        const int* p = (const int*)ei;
        s = p[e];
        d = p[e + N_EDGES];
    }
}

// flag=1 iff data is int64: odd int32 words (high halves) are all zero.
__global__ __launch_bounds__(256) void detect_kernel(const unsigned* ei, int* flagp) {
    __shared__ unsigned red[256];
    unsigned acc = 0;
    for (int i = threadIdx.x; i < 2048; i += 256) acc |= ei[2 * i + 1];
    red[threadIdx.x] = acc;
    __syncthreads();
    if (threadIdx.x == 0) {
        unsigned o = 0;
        for (int i = 0; i < 256; ++i) o |= red[i];
        *flagp = (o == 0) ? 1 : 0;
    }
}

__global__ __launch_bounds__(256) void deg_kernel(const void* ei, const int* flagp, int* deg) {
    const int flag = *flagp;
    int e = blockIdx.x * 256 + threadIdx.x;
    if (e < N_EDGES) {
        int s, d;
        load_edge(ei, flag, e, s, d);
        atomicAdd(&deg[d], 1);
    }
}

__global__ __launch_bounds__(256) void dis_kernel(const int* deg, float* dis) {
    int i = blockIdx.x * 256 + threadIdx.x;
    if (i < N_NODES) dis[i] = rsqrtf((float)deg[i] + 1.0f);
}

// ---- scan phase 1: per-block sums of deg (256 elems/block) ----------------
__global__ __launch_bounds__(256) void scan1_kernel(const int* __restrict__ deg,
                                                    int* __restrict__ bsum) {
    __shared__ int sm[256];
    int i = blockIdx.x * 256 + threadIdx.x;
    int v = (i < N_NODES) ? deg[i] : 0;
    sm[threadIdx.x] = v;
    __syncthreads();
#pragma unroll
    for (int off = 128; off > 0; off >>= 1) {
        if (threadIdx.x < off) sm[threadIdx.x] += sm[threadIdx.x + off];
        __syncthreads();
    }
    if (threadIdx.x == 0) bsum[blockIdx.x] = sm[0];
}

// ---- scan phase 2: exclusive scan of the 196 block sums (1 tiny block) ----
__global__ __launch_bounds__(256) void scan2_kernel(const int* __restrict__ bsum,
                                                    int* __restrict__ ebsum) {
    __shared__ int sm[256];
    int t = threadIdx.x;
    int v = (t < SCAN_B) ? bsum[t] : 0;
    sm[t] = v;
    __syncthreads();
#pragma unroll
    for (int off = 1; off < 256; off <<= 1) {
        int u = (t >= off) ? sm[t - off] : 0;
        __syncthreads();
        sm[t] += u;
        __syncthreads();
    }
    if (t < SCAN_B) ebsum[t] = sm[t] - v;  // exclusive
}

// ---- scan phase 3: intra-block exclusive scan + offset -> rowptr, cursor --
__global__ __launch_bounds__(256) void scan3_kernel(const int* __restrict__ deg,
                                                    const int* __restrict__ ebsum,
                                                    int* __restrict__ rowptr,
                                                    int* __restrict__ cursor) {
    __shared__ int sm[256];
    const int t = threadIdx.x;
    const int i = blockIdx.x * 256 + t;
    int v = (i < N_NODES) ? deg[i] : 0;
    sm[t] = v;
    __syncthreads();
#pragma unroll
    for (int off = 1; off < 256; off <<= 1) {
        int u = (t >= off) ? sm[t - off] : 0;
        __syncthreads();
        sm[t] += u;
        __syncthreads();
    }
    int incl = sm[t];
    int base = ebsum[blockIdx.x];
    if (i < N_NODES) {
        int excl = base + incl - v;
        rowptr[i] = excl;
        cursor[i] = excl;
        if (i == N_NODES - 1) rowptr[N_NODES] = base + incl;
    }
}

// ---- counting-sort scatter: sortedsrc[pos] = src, grouped by dst ----------
__global__ __launch_bounds__(256) void sort_kernel(const void* ei, const int* flagp,
                                                   int* __restrict__ cursor,
                                                   int* __restrict__ sortedsrc) {
    const int flag = *flagp;
    int e = blockIdx.x * 256 + threadIdx.x;
    if (e < N_EDGES) {
        int s, d;
        load_edge(ei, flag, e, s, d);
        int pos = atomicAdd(&cursor[d], 1);
        sortedsrc[pos] = s;
    }
}

// --------------- GEMM1: h1b = bf16(x @ W1) -----------------
// tile: 64 rows x 64 cols, K=128. block 256 threads, 4x4 register tile/thread.
__global__ __launch_bounds__(256) void gemm1_kernel(
        const float* __restrict__ x, const float* __restrict__ W1,
        unsigned short* __restrict__ h1b) {
    extern __shared__ float smem[];
    float (*xs)[132] = (float(*)[132])smem;             // 64 x 132
    float (*wsh)[68] = (float(*)[68])(smem + 64 * 132); // 128 x 68

    const int t = threadIdx.x;
    const int brow = blockIdx.x * 64;

    for (int f = t; f < 2048; f += 256) {
        int r = f >> 4, c = (f & 15) << 2;
        float4 v = ((const float4*)W1)[f];
        *(float4*)&wsh[r][c] = v;
    }
    for (int f = t; f < 2048; f += 256) {
        int r = f >> 5, c = (f & 31) << 2;
        int gr = brow + r;
        float4 v = make_float4(0.f, 0.f, 0.f, 0.f);
        if (gr < N_NODES) v = *(const float4*)(x + gr * IN_CH + c);
        *(float4*)&xs[r][c] = v;
    }
    __syncthreads();

    const int tc = (t & 15) << 2;
    const int tr = (t >> 4) << 2;
    float acc[4][4] = {};
#pragma unroll 4
    for (int k4 = 0; k4 < 32; ++k4) {
        const int k = k4 << 2;
        float xr[4][4], wr[4][4];
#pragma unroll
        for (int i = 0; i < 4; ++i) {
            float4 v = *(const float4*)&xs[tr + i][k];
            xr[i][0] = v.x; xr[i][1] = v.y; xr[i][2] = v.z; xr[i][3] = v.w;
        }
#pragma unroll
        for (int j = 0; j < 4; ++j) {
            float4 v = *(const float4*)&wsh[k + j][tc];
            wr[j][0] = v.x; wr[j][1] = v.y; wr[j][2] = v.z; wr[j][3] = v.w;
        }
#pragma unroll
        for (int i = 0; i < 4; ++i)
#pragma unroll
            for (int c = 0; c < 4; ++c)
                acc[i][c] += xr[i][0] * wr[0][c] + xr[i][1] * wr[1][c]
                           + xr[i][2] * wr[2][c] + xr[i][3] * wr[3][c];
    }

#pragma unroll
    for (int i = 0; i < 4; ++i) {
        int r = brow + tr + i;
        if (r < N_NODES) {
            ushort4 pk;
            pk.x = bf16rne(acc[i][0]); pk.y = bf16rne(acc[i][1]);
            pk.z = bf16rne(acc[i][2]); pk.w = bf16rne(acc[i][3]);
            *(ushort4*)(h1b + r * HID + tc) = pk;
        }
    }
}

// ---- agg1: per dst node, wave of 64 lanes (= HID channels) ----------------
// agg1[d][c] = relu( sum_j h1[src_j][c]*dis[src_j]*dis[d] + h1[d][c]*dis[d]^2 + b1[c] )
__global__ __launch_bounds__(256) void agg1_kernel(
        const int* __restrict__ rowptr, const int* __restrict__ sortedsrc,
        const float* __restrict__ dis, const unsigned short* __restrict__ h1b,
        const float* __restrict__ b1, float* __restrict__ agg1) {
    const int lane = threadIdx.x & 63;
    const int d = blockIdx.x * 4 + (threadIdx.x >> 6);
    if (d >= N_NODES) return;
    const int beg = rowptr[d], end = rowptr[d + 1];
    const float dd = dis[d];
    float a0 = 0.f, a1 = 0.f, a2 = 0.f, a3 = 0.f;
    int j = beg;
    for (; j + 3 < end; j += 4) {
        int s0 = sortedsrc[j], s1 = sortedsrc[j + 1];
        int s2 = sortedsrc[j + 2], s3 = sortedsrc[j + 3];
        float n0 = dis[s0] * dd, n1 = dis[s1] * dd;
        float n2 = dis[s2] * dd, n3 = dis[s3] * dd;
        a0 += bf16f(h1b[s0 * HID + lane]) * n0;
        a1 += bf16f(h1b[s1 * HID + lane]) * n1;
        a2 += bf16f(h1b[s2 * HID + lane]) * n2;
        a3 += bf16f(h1b[s3 * HID + lane]) * n3;
    }
    for (; j < end; ++j) {
        int s0 = sortedsrc[j];
        a0 += bf16f(h1b[s0 * HID + lane]) * (dis[s0] * dd);
    }
    float v = (a0 + a1) + (a2 + a3) + bf16f(h1b[d * HID + lane]) * (dd * dd) + b1[lane];
    agg1[d * HID + lane] = fmaxf(v, 0.f);
}

// --------------- GEMM2: h2b = bf16(agg1 @ W2) (agg1 already relu'ed) -------
// tile: 128 rows x 32 cols, K=64. block 256, 4x4 register tile/thread.
__global__ __launch_bounds__(256) void gemm2_kernel(
        const float* __restrict__ agg1, const float* __restrict__ W2,
        unsigned short* __restrict__ h2b) {
    extern __shared__ float smem[];
    float (*xs)[68] = (float(*)[68])smem;               // 128 x 68
    float (*wsh)[36] = (float(*)[36])(smem + 128 * 68); // 64 x 36

    const int t = threadIdx.x;
    const int brow = blockIdx.x * 128;

    for (int f = t; f < 512; f += 256) {
        int r = f >> 3, c = (f & 7) << 2;
        float4 v = ((const float4*)W2)[f];
        *(float4*)&wsh[r][c] = v;
    }
    for (int f = t; f < 2048; f += 256) {
        int r = f >> 4, c = (f & 15) << 2;
        int gr = brow + r;
        float4 v = make_float4(0.f, 0.f, 0.f, 0.f);
        if (gr < N_NODES) v = *(const float4*)(agg1 + gr * HID + c);
        *(float4*)&xs[r][c] = v;
    }
    __syncthreads();

    const int tc = (t & 7) << 2;
    const int tr = (t >> 3) << 2;
    float acc[4][4] = {};
#pragma unroll 4
    for (int k4 = 0; k4 < 16; ++k4) {
        const int k = k4 << 2;
        float xr[4][4], wr[4][4];
#pragma unroll
        for (int i = 0; i < 4; ++i) {
            float4 v = *(const float4*)&xs[tr + i][k];
            xr[i][0] = v.x; xr[i][1] = v.y; xr[i][2] = v.z; xr[i][3] = v.w;
        }
#pragma unroll
        for (int j = 0; j < 4; ++j) {
            float4 v = *(const float4*)&wsh[k + j][tc];
            wr[j][0] = v.x; wr[j][1] = v.y; wr[j][2] = v.z; wr[j][3] = v.w;
        }
#pragma unroll
        for (int i = 0; i < 4; ++i)
#pragma unroll
            for (int c = 0; c < 4; ++c)
                acc[i][c] += xr[i][0] * wr[0][c] + xr[i][1] * wr[1][c]
                           + xr[i][2] * wr[2][c] + xr[i][3] * wr[3][c];
    }

#pragma unroll
    for (int i = 0; i < 4; ++i) {
        int r = brow + tr + i;
        if (r < N_NODES) {
            ushort4 pk;
            pk.x = bf16rne(acc[i][0]); pk.y = bf16rne(acc[i][1]);
            pk.z = bf16rne(acc[i][2]); pk.w = bf16rne(acc[i][3]);
            *(ushort4*)(h2b + r * OUT_CH + tc) = pk;
        }
    }
}

// ---- agg2: per dst node, one wave; halves handle interleaved edges --------
// out[d][c] = sum_j h2[src_j][c]*norm_j + h2[d][c]*dis[d]^2 + b2[c]
__global__ __launch_bounds__(256) void agg2_kernel(
        const int* __restrict__ rowptr, const int* __restrict__ sortedsrc,
        const float* __restrict__ dis, const unsigned short* __restrict__ h2b,
        const float* __restrict__ b2, float* __restrict__ out) {
    const int lane = threadIdx.x & 63;
    const int c = lane & 31;
    const int half = lane >> 5;
    const int d = blockIdx.x * 4 + (threadIdx.x >> 6);
    if (d >= N_NODES) return;
    const int beg = rowptr[d], end = rowptr[d + 1];
    const float dd = dis[d];
    float a0 = 0.f, a1 = 0.f;
    int j = beg + half;
    for (; j + 2 < end; j += 4) {
        int s0 = sortedsrc[j], s1 = sortedsrc[j + 2];
        a0 += bf16f(h2b[s0 * OUT_CH + c]) * (dis[s0] * dd);
        a1 += bf16f(h2b[s1 * OUT_CH + c]) * (dis[s1] * dd);
    }
    if (j < end) {
        int s0 = sortedsrc[j];
        a0 += bf16f(h2b[s0 * OUT_CH + c]) * (dis[s0] * dd);
    }
    float acc = a0 + a1;
    acc += __shfl_xor(acc, 32, 64);
    if (half == 0) {
        float v = acc + bf16f(h2b[d * OUT_CH + c]) * (dd * dd) + b2[c];
        out[d * OUT_CH + c] = v;
    }
}

extern "C" void kernel_launch(void* const* d_in, const int* in_sizes, int n_in,
                              void* d_out, int out_size, void* d_ws, size_t ws_size,
                              hipStream_t stream) {
    const float* x  = (const float*)d_in[0];
    const float* W1 = (const float*)d_in[1];
    const float* b1 = (const float*)d_in[2];
    const float* W2 = (const float*)d_in[3];
    const float* b2 = (const float*)d_in[4];
    const void*  ei = d_in[5];
    float* out = (float*)d_out;

    char* ws = (char*)d_ws;
    int*   flagp     = (int*)ws;                          // 512 B
    int*   deg       = (int*)(ws + 512);                  // 200704 B
    float* dis       = (float*)(ws + 512 + 200704);       // 200704 B
    int*   rowptr    = (int*)(ws + 512 + 2 * 200704);     // 200704 B (50001 used)
    int*   cursor    = (int*)(ws + 512 + 3 * 200704);     // 200704 B
    int*   bsum      = (int*)(ws + 512 + 4 * 200704);     // 1024 B
    int*   ebsum     = bsum + 256;                        // 1024 B
    int*   sortedsrc = (int*)(ws + 512 + 4 * 200704 + 4096);              // 3.2 MB
    unsigned short* h1b = (unsigned short*)(ws + 512 + 4 * 200704 + 4096 + 3200000);  // 6.4 MB
    float* agg1      = (float*)((char*)h1b + (size_t)N_NODES * HID * 2);  // 12.8 MB
    unsigned short* h2b = (unsigned short*)((char*)agg1 + (size_t)N_NODES * HID * 4); // 3.2 MB

    hipMemsetAsync(deg, 0, N_NODES * sizeof(int), stream);
    detect_kernel<<<1, 256, 0, stream>>>((const unsigned*)ei, flagp);
    deg_kernel<<<(N_EDGES + 255) / 256, 256, 0, stream>>>(ei, flagp, deg);
    dis_kernel<<<(N_NODES + 255) / 256, 256, 0, stream>>>(deg, dis);
    scan1_kernel<<<SCAN_B, 256, 0, stream>>>(deg, bsum);
    scan2_kernel<<<1, 256, 0, stream>>>(bsum, ebsum);
    scan3_kernel<<<SCAN_B, 256, 0, stream>>>(deg, ebsum, rowptr, cursor);
    sort_kernel<<<(N_EDGES + 255) / 256, 256, 0, stream>>>(ei, flagp, cursor, sortedsrc);

    size_t sh1 = (64 * 132 + 128 * 68) * sizeof(float);
    gemm1_kernel<<<(N_NODES + 63) / 64, 256, sh1, stream>>>(x, W1, h1b);

    agg1_kernel<<<(N_NODES + 3) / 4, 256, 0, stream>>>(rowptr, sortedsrc, dis, h1b, b1, agg1);

    size_t sh2 = (128 * 68 + 64 * 36) * sizeof(float);
    gemm2_kernel<<<(N_NODES + 127) / 128, 256, sh2, stream>>>(agg1, W2, h2b);

    agg2_kernel<<<(N_NODES + 3) / 4, 256, 0, stream>>>(rowptr, sortedsrc, dis, h2b, b2, out);
}